// Round 1
// baseline (786.772 us; speedup 1.0000x reference)
//
#include <hip/hip_runtime.h>
#include <hip/hip_bf16.h>
#include <stdint.h>

// Problem constants
#define B_    4
#define S_    4096
#define DIM_  2048
#define H_    16
#define HD_   128
#define M_    (B_ * S_)     // 16384 rows
#define K_    DIM_          // 2048
#define N_    (3 * DIM_)    // 6144 (q|k|v concatenated)

typedef __attribute__((ext_vector_type(8))) short bf16x8;
typedef __attribute__((ext_vector_type(4))) float f32x4;

// ---------------------------------------------------------------------------
// Kernel 1: X fp32 -> bf16  (33.5M elems, 8 per thread)
// ---------------------------------------------------------------------------
__global__ void cvt_x_kernel(const float* __restrict__ X,
                             __hip_bfloat16* __restrict__ Xb) {
    size_t i = ((size_t)blockIdx.x * 256 + threadIdx.x) * 8;
    float4 a = *reinterpret_cast<const float4*>(X + i);
    float4 b = *reinterpret_cast<const float4*>(X + i + 4);
    union { __hip_bfloat16 h[8]; uint4 u; } o;
    o.h[0] = __float2bfloat16(a.x);
    o.h[1] = __float2bfloat16(a.y);
    o.h[2] = __float2bfloat16(a.z);
    o.h[3] = __float2bfloat16(a.w);
    o.h[4] = __float2bfloat16(b.x);
    o.h[5] = __float2bfloat16(b.y);
    o.h[6] = __float2bfloat16(b.z);
    o.h[7] = __float2bfloat16(b.w);
    *reinterpret_cast<uint4*>(Xb + i) = o.u;
}

// ---------------------------------------------------------------------------
// Kernel 2: Wt[n][k] = W_sel[k][n] cast to bf16  (B^T layout for the GEMM)
// blockIdx.z selects Wq/Wk/Wv; 32x32 tiles, block (32,8)
// ---------------------------------------------------------------------------
__global__ void cvt_w_kernel(const float* __restrict__ Wq,
                             const float* __restrict__ Wk,
                             const float* __restrict__ Wv,
                             __hip_bfloat16* __restrict__ Wt) {
    __shared__ float tile[32][33];
    int w = blockIdx.z;
    const float* W = (w == 0) ? Wq : (w == 1) ? Wk : Wv;
    int n0 = blockIdx.x * 32;   // column of W (= row of Wt within region)
    int k0 = blockIdx.y * 32;   // row of W
    int tx = threadIdx.x, ty = threadIdx.y;
#pragma unroll
    for (int r = 0; r < 4; ++r) {
        int k = k0 + ty + r * 8;
        tile[ty + r * 8][tx] = W[(size_t)k * DIM_ + n0 + tx];
    }
    __syncthreads();
#pragma unroll
    for (int r = 0; r < 4; ++r) {
        int n = n0 + ty + r * 8;
        Wt[(size_t)(w * DIM_ + n) * K_ + k0 + tx] =
            __float2bfloat16(tile[tx][ty + r * 8]);
    }
}

// ---------------------------------------------------------------------------
// Kernel 3: bf16 GEMM (m97 structure) + fused interleaved RoPE epilogue
//   C[m][n] = sum_k Xb[m][k] * Wt[n][k],  n in [0,6144)
//   region = n/2048: 0->Q(+RoPE), 1->K(+RoPE), 2->V(copy)
// 128x128 tile, BK=64, 4 waves, global_load_lds width 16, 16x16x32 MFMA
// ---------------------------------------------------------------------------
#define BM 128
#define BN 128
#define BK 64

__global__ __launch_bounds__(256) void gemm_rope_kernel(
    const __hip_bfloat16* __restrict__ Xb,   // [M_][K_]
    const __hip_bfloat16* __restrict__ Wt,   // [N_][K_]
    const float* __restrict__ fcos,          // [S_][HD_]
    const float* __restrict__ fsin,          // [S_][HD_]
    float* __restrict__ out)                 // 3 regions of [M_][DIM_]
{
    __shared__ __hip_bfloat16 As[BM * BK];   // 16 KB, row-major [128][64]
    __shared__ __hip_bfloat16 Bs[BN * BK];   // 16 KB, [n][k]

    // XCD-aware bijective swizzle (gridDim = 6144, 6144 % 8 == 0)
    const int nbn = N_ / BN;                 // 48
    int bid = blockIdx.x;
    int cpx = gridDim.x >> 3;
    int swz = (bid & 7) * cpx + (bid >> 3);
    int tm = swz / nbn, tn = swz % nbn;
    int m0 = tm * BM, n0 = tn * BN;

    int tid  = threadIdx.x;
    int lane = tid & 63;
    int wid  = tid >> 6;                     // 0..3
    int wm   = (wid >> 1) * 64;              // wave row offset in tile
    int wn   = (wid & 1) * 64;               // wave col offset in tile

    // staging decomposition: wave wid, chunk c covers rows wid*32 + c*8 + lane/8
    int lrow = lane >> 3;                    // 0..7
    int lk   = (lane & 7) * 8;               // k element offset (16B granules)

    f32x4 acc[4][4] = {};

    for (int k0i = 0; k0i < K_; k0i += BK) {
#pragma unroll
        for (int c = 0; c < 4; ++c) {
            int row = wid * 32 + c * 8 + lrow;             // 0..127
            const __hip_bfloat16* ga = Xb + (size_t)(m0 + row) * K_ + k0i + lk;
            __builtin_amdgcn_global_load_lds(
                (const __attribute__((address_space(1))) void*)ga,
                (__attribute__((address_space(3))) void*)(As + row * BK + lk),
                16, 0, 0);
            const __hip_bfloat16* gb = Wt + (size_t)(n0 + row) * K_ + k0i + lk;
            __builtin_amdgcn_global_load_lds(
                (const __attribute__((address_space(1))) void*)gb,
                (__attribute__((address_space(3))) void*)(Bs + row * BK + lk),
                16, 0, 0);
        }
        __syncthreads();

        int fr = lane & 15;                  // fragment row (A) / col (B)
        int fk = (lane >> 4) * 8;            // fragment k offset
#pragma unroll
        for (int kk = 0; kk < BK; kk += 32) {
            bf16x8 af[4], bfr[4];
#pragma unroll
            for (int i = 0; i < 4; ++i)
                af[i] = *reinterpret_cast<const bf16x8*>(
                    As + (wm + i * 16 + fr) * BK + kk + fk);
#pragma unroll
            for (int j = 0; j < 4; ++j)
                bfr[j] = *reinterpret_cast<const bf16x8*>(
                    Bs + (wn + j * 16 + fr) * BK + kk + fk);
#pragma unroll
            for (int i = 0; i < 4; ++i)
#pragma unroll
                for (int j = 0; j < 4; ++j)
                    acc[i][j] = __builtin_amdgcn_mfma_f32_16x16x32_bf16(
                        af[i], bfr[j], acc[i][j], 0, 0, 0);
        }
        __syncthreads();
    }

    // Epilogue: C/D layout (16x16): col = lane&15, row = (lane>>4)*4 + r
    int fr = lane & 15;
    int fq = lane >> 4;
#pragma unroll
    for (int i = 0; i < 4; ++i) {
        int mbase = m0 + wm + i * 16 + fq * 4;
#pragma unroll
        for (int j = 0; j < 4; ++j) {
            int c  = n0 + wn + j * 16 + fr;
            int region = c >> 11;            // 0=q,1=k,2=v
            int cc = c & (DIM_ - 1);
            int d  = cc & (HD_ - 1);
#pragma unroll
            for (int r = 0; r < 4; ++r) {
                int m = mbase + r;
                int s = m & (S_ - 1);
                float g  = acc[i][j][r];
                float gp = __shfl_xor(g, 1, 64);  // pair partner (col^1)
                float o;
                if (region < 2) {
                    float cv = fcos[s * HD_ + d];
                    float sv = fsin[s * HD_ + d];
                    // even d: g*cos - partner*sin ; odd d: g*cos + partner*sin
                    o = g * cv + ((cc & 1) ? gp * sv : -gp * sv);
                } else {
                    o = g;
                }
                out[(size_t)region * M_ * DIM_ + (size_t)m * DIM_ + cc] = o;
            }
        }
    }
}

// ---------------------------------------------------------------------------
extern "C" void kernel_launch(void* const* d_in, const int* in_sizes, int n_in,
                              void* d_out, int out_size, void* d_ws, size_t ws_size,
                              hipStream_t stream) {
    const float* X    = (const float*)d_in[0];
    const float* fcos = (const float*)d_in[1];
    const float* fsin = (const float*)d_in[2];
    // d_in[3] = attention_mask (all ones, unused by the reference math)
    const float* Wq   = (const float*)d_in[4];
    const float* Wk   = (const float*)d_in[5];
    const float* Wv   = (const float*)d_in[6];
    float* out = (float*)d_out;

    // workspace layout: Xb (bf16, M_*K_) | Wt (bf16, N_*K_)
    __hip_bfloat16* Xb = (__hip_bfloat16*)d_ws;
    __hip_bfloat16* Wt = Xb + (size_t)M_ * K_;

    // 1) X -> bf16
    {
        int threads = 256;
        int blocks = (M_ * K_) / (threads * 8);   // 16384
        cvt_x_kernel<<<blocks, threads, 0, stream>>>(X, Xb);
    }
    // 2) W -> bf16 transposed, fused q|k|v
    {
        dim3 grid(DIM_ / 32, DIM_ / 32, 3);
        dim3 block(32, 8);
        cvt_w_kernel<<<grid, block, 0, stream>>>(Wq, Wk, Wv, Wt);
    }
    // 3) GEMM + RoPE
    {
        int blocks = (M_ / BM) * (N_ / BN);       // 128 * 48 = 6144
        gemm_rope_kernel<<<blocks, 256, 0, stream>>>(Xb, Wt, fcos, fsin, out);
    }
}

// Round 2
// 589.889 us; speedup vs baseline: 1.3338x; 1.3338x over previous
//
#include <hip/hip_runtime.h>
#include <hip/hip_bf16.h>
#include <stdint.h>

// Problem constants
#define B_    4
#define S_    4096
#define DIM_  2048
#define H_    16
#define HD_   128
#define M_    (B_ * S_)     // 16384 rows
#define K_    DIM_          // 2048
#define N_    (3 * DIM_)    // 6144 (q|k|v concatenated)

typedef __attribute__((ext_vector_type(8))) short bf16x8;
typedef __attribute__((ext_vector_type(4))) float f32x4;

// ---------------------------------------------------------------------------
// Kernel 1: X fp32 -> bf16  (33.5M elems, 8 per thread)
// ---------------------------------------------------------------------------
__global__ void cvt_x_kernel(const float* __restrict__ X,
                             __hip_bfloat16* __restrict__ Xb) {
    size_t i = ((size_t)blockIdx.x * 256 + threadIdx.x) * 8;
    float4 a = *reinterpret_cast<const float4*>(X + i);
    float4 b = *reinterpret_cast<const float4*>(X + i + 4);
    union { __hip_bfloat16 h[8]; uint4 u; } o;
    o.h[0] = __float2bfloat16(a.x);
    o.h[1] = __float2bfloat16(a.y);
    o.h[2] = __float2bfloat16(a.z);
    o.h[3] = __float2bfloat16(a.w);
    o.h[4] = __float2bfloat16(b.x);
    o.h[5] = __float2bfloat16(b.y);
    o.h[6] = __float2bfloat16(b.z);
    o.h[7] = __float2bfloat16(b.w);
    *reinterpret_cast<uint4*>(Xb + i) = o.u;
}

// ---------------------------------------------------------------------------
// Kernel 2: Wt[n][k] = W_sel[k][n] cast to bf16  (B^T layout for the GEMM)
// ---------------------------------------------------------------------------
__global__ void cvt_w_kernel(const float* __restrict__ Wq,
                             const float* __restrict__ Wk,
                             const float* __restrict__ Wv,
                             __hip_bfloat16* __restrict__ Wt) {
    __shared__ float tile[32][33];
    int w = blockIdx.z;
    const float* W = (w == 0) ? Wq : (w == 1) ? Wk : Wv;
    int n0 = blockIdx.x * 32;
    int k0 = blockIdx.y * 32;
    int tx = threadIdx.x, ty = threadIdx.y;
#pragma unroll
    for (int r = 0; r < 4; ++r) {
        int k = k0 + ty + r * 8;
        tile[ty + r * 8][tx] = W[(size_t)k * DIM_ + n0 + tx];
    }
    __syncthreads();
#pragma unroll
    for (int r = 0; r < 4; ++r) {
        int n = n0 + ty + r * 8;
        Wt[(size_t)(w * DIM_ + n) * K_ + k0 + tx] =
            __float2bfloat16(tile[tx][ty + r * 8]);
    }
}

// ---------------------------------------------------------------------------
// Kernel 3: 256x256 8-phase bf16 GEMM (T1+T2+T3+T4+T5) + fused RoPE epilogue
//   C[m][n] = sum_k Xb[m][k] * Wt[n][k]
// 8 waves (2M x 4N), BK=64, 2x double-buffered LDS (128 KiB), granule-XOR
// swizzle (linear LDS dest + pre-swizzled global src + swizzled ds_read),
// counted vmcnt (never 0 in steady state), raw asm barriers, setprio(1)
// around MFMA clusters.
// ---------------------------------------------------------------------------
#define BM 256
#define BN 256
#define BK 64
#define NT (K_ / BK)   // 32

#define BAR()      asm volatile("s_barrier" ::: "memory")
#define LGKM0()    asm volatile("s_waitcnt lgkmcnt(0)" ::: "memory")
#define WAIT_VM(n) asm volatile("s_waitcnt vmcnt(" #n ")" ::: "memory")

__global__ __launch_bounds__(512, 1) void gemm_rope_kernel(
    const __hip_bfloat16* __restrict__ Xb,   // [M_][K_]
    const __hip_bfloat16* __restrict__ Wt,   // [N_][K_]
    const float* __restrict__ fcos,          // [S_][HD_]
    const float* __restrict__ fsin,          // [S_][HD_]
    float* __restrict__ out)                 // 3 regions of [M_][DIM_]
{
    __shared__ __hip_bfloat16 As[2][BM * BK];   // 2 x 32 KB
    __shared__ __hip_bfloat16 Bs[2][BN * BK];   // 2 x 32 KB

    // T1: XCD-aware bijective swizzle (grid = 1536, 1536 % 8 == 0)
    const int nbn = N_ / BN;                 // 24
    int bid = blockIdx.x;
    int cpx = gridDim.x >> 3;                // 192
    int swz = (bid & 7) * cpx + (bid >> 3);
    int tm = swz / nbn, tn = swz % nbn;
    int m0 = tm * BM, n0 = tn * BN;

    int tid  = threadIdx.x;
    int lane = tid & 63;
    int w    = tid >> 6;                     // 0..7
    int wr   = w >> 2;                       // 0..1  (row half, 128 rows)
    int wc   = w & 3;                        // 0..3  (col quarter, 64 cols)

    // staging lane decomposition: 8 rows x 8 granules(16B) per wave-issue
    int rl   = lane >> 3;                    // 0..7 row within 8
    int gsw  = ((lane & 7) ^ rl) * 8;        // pre-swizzled source col (elems)
    int lcol = (lane & 7) * 8;               // linear LDS col (elems)

    // fragment-read constants
    int fr = lane & 15;                      // frag row/col
    int fq = lane >> 4;                      // 0..3 (k granule within 32)
    int l7 = lane & 7;
    int ce0 = ((0 + fq) ^ l7) * 8;           // swizzled col elems, kk=0
    int ce1 = ((4 + fq) ^ l7) * 8;           // swizzled col elems, kk=32

    // --- staging helpers (one global_load_lds = 8 rows x 64 cols per wave) ---
#define STAGE_A(t, r) do {                                                     \
        const __hip_bfloat16* _s = Xb + (size_t)(m0 + (r) * 64 + w * 8 + rl) * K_ \
                                      + (t) * BK + gsw;                        \
        __hip_bfloat16* _d = &As[(t) & 1][((r) * 64 + w * 8 + rl) * BK + lcol];\
        __builtin_amdgcn_global_load_lds(                                      \
            (const __attribute__((address_space(1))) void*)_s,                 \
            (__attribute__((address_space(3))) void*)_d, 16, 0, 0);            \
    } while (0)

#define STAGE_B(t, r) do {                                                     \
        const __hip_bfloat16* _s = Wt + (size_t)(n0 + (r) * 64 + w * 8 + rl) * K_ \
                                      + (t) * BK + gsw;                        \
        __hip_bfloat16* _d = &Bs[(t) & 1][((r) * 64 + w * 8 + rl) * BK + lcol];\
        __builtin_amdgcn_global_load_lds(                                      \
            (const __attribute__((address_space(1))) void*)_s,                 \
            (__attribute__((address_space(3))) void*)_d, 16, 0, 0);            \
    } while (0)

    f32x4  acc[2][2][4][2] = {};             // [qi][qj][i][j]
    bf16x8 a[4][2];                          // A frags: [i][kk]   (row half qi)
    bf16x8 b[2][2][2];                       // B frags: [qj][j][kk]

#define LDA(buf, qi) do {                                                      \
        _Pragma("unroll")                                                      \
        for (int i = 0; i < 4; ++i) {                                          \
            int _row = wr * 128 + (qi) * 64 + i * 16 + fr;                     \
            a[i][0] = *reinterpret_cast<const bf16x8*>(&As[buf][_row * BK + ce0]); \
            a[i][1] = *reinterpret_cast<const bf16x8*>(&As[buf][_row * BK + ce1]); \
        }                                                                      \
    } while (0)

#define LDB(buf, qj) do {                                                      \
        _Pragma("unroll")                                                      \
        for (int j = 0; j < 2; ++j) {                                          \
            int _row = wc * 64 + (qj) * 32 + j * 16 + fr;                      \
            b[qj][j][0] = *reinterpret_cast<const bf16x8*>(&Bs[buf][_row * BK + ce0]); \
            b[qj][j][1] = *reinterpret_cast<const bf16x8*>(&Bs[buf][_row * BK + ce1]); \
        }                                                                      \
    } while (0)

#define MFMA_Q(qi, qj) do {                                                    \
        __builtin_amdgcn_s_setprio(1);                                         \
        _Pragma("unroll")                                                      \
        for (int i = 0; i < 4; ++i)                                            \
        _Pragma("unroll")                                                      \
        for (int j = 0; j < 2; ++j) {                                          \
            acc[qi][qj][i][j] = __builtin_amdgcn_mfma_f32_16x16x32_bf16(       \
                a[i][0], b[qj][j][0], acc[qi][qj][i][j], 0, 0, 0);             \
            acc[qi][qj][i][j] = __builtin_amdgcn_mfma_f32_16x16x32_bf16(       \
                a[i][1], b[qj][j][1], acc[qi][qj][i][j], 0, 0, 0);             \
        }                                                                      \
        __builtin_amdgcn_s_setprio(0);                                         \
    } while (0)

    // ---------------- prologue: stage A(0), B(0), A(1) ----------------------
#pragma unroll
    for (int r = 0; r < 4; ++r) STAGE_A(0, r);
#pragma unroll
    for (int r = 0; r < 4; ++r) STAGE_B(0, r);
#pragma unroll
    for (int r = 0; r < 4; ++r) STAGE_A(1, r);
    WAIT_VM(4);                               // A(0), B(0) landed; A(1) in flight
    BAR();

    // ---------------- main loop: 4 phases per K-tile ------------------------
    for (int t = 0; t < NT; ++t) {
        int buf = t & 1;
        // phase 0: read A half 0 + B half 0; stage B(t+1) rounds 0,1
        LDA(buf, 0);
        LDB(buf, 0);
        if (t + 1 < NT) { STAGE_B(t + 1, 0); STAGE_B(t + 1, 1); }
        BAR(); LGKM0();
        MFMA_Q(0, 0);
        BAR();
        // phase 1: read B half 1; stage B(t+1) rounds 2,3
        LDB(buf, 1);
        if (t + 1 < NT) { STAGE_B(t + 1, 2); STAGE_B(t + 1, 3); }
        BAR(); LGKM0();
        MFMA_Q(0, 1);
        BAR();
        // phase 2: read A half 1 (A reads of this buffer end here)
        LDA(buf, 1);
        BAR(); LGKM0();
        MFMA_Q(1, 0);
        BAR();
        // phase 3: stage A(t+2) (safe: after ph2 barrier, all A reads done)
        if (t + 2 < NT) {
            STAGE_A(t + 2, 0); STAGE_A(t + 2, 1);
            STAGE_A(t + 2, 2); STAGE_A(t + 2, 3);
        }
        BAR(); LGKM0();
        MFMA_Q(1, 1);
        // boundary wait: guarantee A(t+1)+B(t+1) landed; keep A(t+2) in flight
        if (t + 2 < NT) { WAIT_VM(4); } else { WAIT_VM(0); }
        BAR();
    }

    // ---------------- epilogue: RoPE + store --------------------------------
    // C/D layout (16x16): col = lane&15 (=fr), row = (lane>>4)*4 + r (=fq*4+r)
#pragma unroll
    for (int qi = 0; qi < 2; ++qi)
#pragma unroll
    for (int i = 0; i < 4; ++i) {
        int mbase = m0 + wr * 128 + qi * 64 + i * 16 + fq * 4;
#pragma unroll
        for (int qj = 0; qj < 2; ++qj)
#pragma unroll
        for (int j = 0; j < 2; ++j) {
            int n = n0 + wc * 64 + qj * 32 + j * 16 + fr;
            int region = n >> 11;            // 0=q,1=k,2=v
            int cc = n & (DIM_ - 1);
            int d  = cc & (HD_ - 1);
#pragma unroll
            for (int r = 0; r < 4; ++r) {
                int m = mbase + r;
                int s = m & (S_ - 1);
                float g  = acc[qi][qj][i][j][r];
                float gp = __shfl_xor(g, 1, 64);  // interleaved pair partner
                float o;
                if (region < 2) {
                    float cv = fcos[s * HD_ + d];
                    float sv = fsin[s * HD_ + d];
                    o = g * cv + ((cc & 1) ? gp * sv : -gp * sv);
                } else {
                    o = g;
                }
                out[(size_t)region * M_ * DIM_ + (size_t)m * DIM_ + cc] = o;
            }
        }
    }
#undef STAGE_A
#undef STAGE_B
#undef LDA
#undef LDB
#undef MFMA_Q
}

// ---------------------------------------------------------------------------
extern "C" void kernel_launch(void* const* d_in, const int* in_sizes, int n_in,
                              void* d_out, int out_size, void* d_ws, size_t ws_size,
                              hipStream_t stream) {
    const float* X    = (const float*)d_in[0];
    const float* fcos = (const float*)d_in[1];
    const float* fsin = (const float*)d_in[2];
    // d_in[3] = attention_mask (all ones, unused by the reference math)
    const float* Wq   = (const float*)d_in[4];
    const float* Wk   = (const float*)d_in[5];
    const float* Wv   = (const float*)d_in[6];
    float* out = (float*)d_out;

    __hip_bfloat16* Xb = (__hip_bfloat16*)d_ws;
    __hip_bfloat16* Wtp = Xb + (size_t)M_ * K_;

    {
        int threads = 256;
        int blocks = (M_ * K_) / (threads * 8);   // 16384
        cvt_x_kernel<<<blocks, threads, 0, stream>>>(X, Xb);
    }
    {
        dim3 grid(DIM_ / 32, DIM_ / 32, 3);
        dim3 block(32, 8);
        cvt_w_kernel<<<grid, block, 0, stream>>>(Wq, Wk, Wv, Wtp);
    }
    {
        int blocks = (M_ / BM) * (N_ / BN);       // 64 * 24 = 1536
        gemm_rope_kernel<<<blocks, 512, 0, stream>>>(Xb, Wtp, fcos, fsin, out);
    }
}

// Round 3
// 572.942 us; speedup vs baseline: 1.3732x; 1.0296x over previous
//
#include <hip/hip_runtime.h>
#include <hip/hip_bf16.h>
#include <stdint.h>

// Problem constants
#define B_    4
#define S_    4096
#define DIM_  2048
#define H_    16
#define HD_   128
#define M_    (B_ * S_)     // 16384 rows
#define K_    DIM_          // 2048
#define N_    (3 * DIM_)    // 6144 (q|k|v concatenated)

typedef __attribute__((ext_vector_type(8))) short bf16x8;
typedef __attribute__((ext_vector_type(4))) float f32x4;

// ---------------------------------------------------------------------------
// Kernel 1: X fp32 -> bf16
// ---------------------------------------------------------------------------
__global__ void cvt_x_kernel(const float* __restrict__ X,
                             __hip_bfloat16* __restrict__ Xb) {
    size_t i = ((size_t)blockIdx.x * 256 + threadIdx.x) * 8;
    float4 a = *reinterpret_cast<const float4*>(X + i);
    float4 b = *reinterpret_cast<const float4*>(X + i + 4);
    union { __hip_bfloat16 h[8]; uint4 u; } o;
    o.h[0] = __float2bfloat16(a.x);
    o.h[1] = __float2bfloat16(a.y);
    o.h[2] = __float2bfloat16(a.z);
    o.h[3] = __float2bfloat16(a.w);
    o.h[4] = __float2bfloat16(b.x);
    o.h[5] = __float2bfloat16(b.y);
    o.h[6] = __float2bfloat16(b.z);
    o.h[7] = __float2bfloat16(b.w);
    *reinterpret_cast<uint4*>(Xb + i) = o.u;
}

// ---------------------------------------------------------------------------
// Kernel 2: Wt[n][k] = W_sel[k][n] cast to bf16  (B^T layout)
// ---------------------------------------------------------------------------
__global__ void cvt_w_kernel(const float* __restrict__ Wq,
                             const float* __restrict__ Wk,
                             const float* __restrict__ Wv,
                             __hip_bfloat16* __restrict__ Wt) {
    __shared__ float tile[32][33];
    int w = blockIdx.z;
    const float* W = (w == 0) ? Wq : (w == 1) ? Wk : Wv;
    int n0 = blockIdx.x * 32;
    int k0 = blockIdx.y * 32;
    int tx = threadIdx.x, ty = threadIdx.y;
#pragma unroll
    for (int r = 0; r < 4; ++r) {
        int k = k0 + ty + r * 8;
        tile[ty + r * 8][tx] = W[(size_t)k * DIM_ + n0 + tx];
    }
    __syncthreads();
#pragma unroll
    for (int r = 0; r < 4; ++r) {
        int n = n0 + ty + r * 8;
        Wt[(size_t)(w * DIM_ + n) * K_ + k0 + tx] =
            __float2bfloat16(tile[tx][ty + r * 8]);
    }
}

// ---------------------------------------------------------------------------
// Kernel 3: 256x256 faithful 8-phase (2 K-tiles/iter) bf16 GEMM + RoPE
// 8 waves (2M x 4N), BK=64, compile-time double-buffer, granule-XOR swizzle
// (linear LDS dest + pre-swizzled global src + swizzled ds_read), one
// half-tile staged per phase, vmcnt(4) only at phases 4/8, setprio on MFMA.
// ---------------------------------------------------------------------------
#define BM 256
#define BN 256
#define BK 64
#define NT (K_ / BK)    // 32
#define NU (NT / 2)     // 16 iterations, 2 K-tiles each

#define BAR()      asm volatile("s_barrier" ::: "memory")
#define LGKM0()    asm volatile("s_waitcnt lgkmcnt(0)" ::: "memory")
#define LGKM8()    asm volatile("s_waitcnt lgkmcnt(8)" ::: "memory")
#define WAIT_VM(n) asm volatile("s_waitcnt vmcnt(" #n ")" ::: "memory")

__global__ __launch_bounds__(512, 1) void gemm_rope_kernel(
    const __hip_bfloat16* __restrict__ Xb,   // [M_][K_]
    const __hip_bfloat16* __restrict__ Wt,   // [N_][K_]
    const float* __restrict__ fcos,          // [S_][HD_]
    const float* __restrict__ fsin,          // [S_][HD_]
    float* __restrict__ out)                 // 3 regions of [M_][DIM_]
{
    __shared__ __hip_bfloat16 As[2][BM * BK];   // 2 x 32 KB
    __shared__ __hip_bfloat16 Bs[2][BN * BK];   // 2 x 32 KB

    // T1: XCD-aware bijective swizzle (grid = 1536, 1536 % 8 == 0)
    const int nbn = N_ / BN;                 // 24
    int bid = blockIdx.x;
    int cpx = gridDim.x >> 3;
    int swz = (bid & 7) * cpx + (bid >> 3);
    int tm = swz / nbn, tn = swz % nbn;
    int m0 = tm * BM, n0 = tn * BN;

    int tid  = threadIdx.x;
    int lane = tid & 63;
    int w    = tid >> 6;                     // 0..7
    int wr   = w >> 2;                       // 0..1  row half (128 rows)
    int wc   = w & 3;                        // 0..3  col quarter (64 cols)

    // staging lane decomposition: 8 rows x 8 granules(16B) per wave-issue
    int rl   = lane >> 3;                    // row within 8
    int gsw  = ((lane & 7) ^ rl) * 8;        // pre-swizzled source col (elems)
    int lcol = (lane & 7) * 8;               // linear LDS col (elems)

    // fragment-read constants
    int fr = lane & 15;
    int fq = lane >> 4;                      // k granule within 32
    int l7 = lane & 7;
    int ce0 = ((0 + fq) ^ l7) * 8;           // swizzled col, kk=0
    int ce1 = ((4 + fq) ^ l7) * 8;           // swizzled col, kk=32

    // one stage op = 64 rows x 64 cols (1 global_load_lds per wave); r in 0..3
#define STAGE_A(t, bb, r) do {                                                 \
        const __hip_bfloat16* _s = Xb + (size_t)(m0 + (r) * 64 + w * 8 + rl) * K_ \
                                      + (t) * BK + gsw;                        \
        __hip_bfloat16* _d = &As[bb][((r) * 64 + w * 8 + rl) * BK + lcol];     \
        __builtin_amdgcn_global_load_lds(                                      \
            (const __attribute__((address_space(1))) void*)_s,                 \
            (__attribute__((address_space(3))) void*)_d, 16, 0, 0);            \
    } while (0)

#define STAGE_B(t, bb, r) do {                                                 \
        const __hip_bfloat16* _s = Wt + (size_t)(n0 + (r) * 64 + w * 8 + rl) * K_ \
                                      + (t) * BK + gsw;                        \
        __hip_bfloat16* _d = &Bs[bb][((r) * 64 + w * 8 + rl) * BK + lcol];     \
        __builtin_amdgcn_global_load_lds(                                      \
            (const __attribute__((address_space(1))) void*)_s,                 \
            (__attribute__((address_space(3))) void*)_d, 16, 0, 0);            \
    } while (0)

    f32x4  acc[2][2][4][2] = {};             // [qi][qj][i][j]
    bf16x8 a[4][2];                          // A frags for current qi
    bf16x8 b[2][2][2];                       // B frags [qj][j][kk]

#define LDA(bb, qi) do {                                                       \
        _Pragma("unroll")                                                      \
        for (int i = 0; i < 4; ++i) {                                          \
            int _row = wr * 128 + (qi) * 64 + i * 16 + fr;                     \
            a[i][0] = *reinterpret_cast<const bf16x8*>(&As[bb][_row * BK + ce0]); \
            a[i][1] = *reinterpret_cast<const bf16x8*>(&As[bb][_row * BK + ce1]); \
        }                                                                      \
    } while (0)

#define LDB(bb, qj) do {                                                       \
        _Pragma("unroll")                                                      \
        for (int j = 0; j < 2; ++j) {                                          \
            int _row = wc * 64 + (qj) * 32 + j * 16 + fr;                      \
            b[qj][j][0] = *reinterpret_cast<const bf16x8*>(&Bs[bb][_row * BK + ce0]); \
            b[qj][j][1] = *reinterpret_cast<const bf16x8*>(&Bs[bb][_row * BK + ce1]); \
        }                                                                      \
    } while (0)

#define MFMA_Q(qi, qj) do {                                                    \
        __builtin_amdgcn_s_setprio(1);                                         \
        _Pragma("unroll")                                                      \
        for (int i = 0; i < 4; ++i)                                            \
        _Pragma("unroll")                                                      \
        for (int j = 0; j < 2; ++j) {                                          \
            acc[qi][qj][i][j] = __builtin_amdgcn_mfma_f32_16x16x32_bf16(       \
                a[i][0], b[qj][j][0], acc[qi][qj][i][j], 0, 0, 0);             \
            acc[qi][qj][i][j] = __builtin_amdgcn_mfma_f32_16x16x32_bf16(       \
                a[i][1], b[qj][j][1], acc[qi][qj][i][j], 0, 0, 0);             \
        }                                                                      \
        __builtin_amdgcn_s_setprio(0);                                         \
    } while (0)

    // -------- prologue: A(0)->buf0, B(0)->buf0, B(1)->buf1 ------------------
#pragma unroll
    for (int r = 0; r < 4; ++r) STAGE_A(0, 0, r);
#pragma unroll
    for (int r = 0; r < 4; ++r) STAGE_B(0, 0, r);
#pragma unroll
    for (int r = 0; r < 4; ++r) STAGE_B(1, 1, r);
    WAIT_VM(4);                              // A(0),B(0) landed; B(1) in flight
    BAR();

    // -------- main loop: 8 phases / 2 K-tiles -------------------------------
    // Stage placement (hazard-safe):
    //   ph1: A(T1).h0->buf1   ph2: A(T1).h1      (buf1.A retired prev ph7)
    //   ph3: B(T0+2).h0->buf0 (buf0.B retired ph2)
    //   ph4: A(T0+2).h0->buf0 (buf0.A retired ph3)
    //   ph5: A(T0+2).h1       ph6: B(T0+2).h1
    //   ph7: B(T1+2).h0->buf1 (buf1.B retired ph6)  ph8: B(T1+2).h1
    // vmcnt(4) at ph4/ph8: FIFO of 12 outstanding; oldest 8 = next tile's A+B.
    for (int u = 0; u < NU; ++u) {
        int T0 = 2 * u, T1 = 2 * u + 1;
        bool last = (u == NU - 1);
        // ph1: T0 quad (0,0)
        LDA(0, 0); LDB(0, 0);
        STAGE_A(T1, 1, 0); STAGE_A(T1, 1, 1);
        LGKM8();
        BAR(); LGKM0();
        MFMA_Q(0, 0);
        BAR();
        // ph2: T0 quad (0,1)
        LDB(0, 1);
        STAGE_A(T1, 1, 2); STAGE_A(T1, 1, 3);
        BAR(); LGKM0();
        MFMA_Q(0, 1);
        BAR();
        // ph3: T0 quad (1,0)
        LDA(0, 1);
        if (!last) { STAGE_B(T0 + 2, 0, 0); STAGE_B(T0 + 2, 0, 1); }
        BAR(); LGKM0();
        MFMA_Q(1, 0);
        BAR();
        // ph4: T0 quad (1,1)
        if (!last) { STAGE_A(T0 + 2, 0, 0); STAGE_A(T0 + 2, 0, 1); }
        BAR();
        MFMA_Q(1, 1);
        if (last) { WAIT_VM(0); } else { WAIT_VM(4); }
        BAR();
        // ph5: T1 quad (0,0)
        LDA(1, 0); LDB(1, 0);
        if (!last) { STAGE_A(T0 + 2, 0, 2); STAGE_A(T0 + 2, 0, 3); }
        LGKM8();
        BAR(); LGKM0();
        MFMA_Q(0, 0);
        BAR();
        // ph6: T1 quad (0,1)
        LDB(1, 1);
        if (!last) { STAGE_B(T0 + 2, 0, 2); STAGE_B(T0 + 2, 0, 3); }
        BAR(); LGKM0();
        MFMA_Q(0, 1);
        BAR();
        // ph7: T1 quad (1,0)
        LDA(1, 1);
        if (!last) { STAGE_B(T1 + 2, 1, 0); STAGE_B(T1 + 2, 1, 1); }
        BAR(); LGKM0();
        MFMA_Q(1, 0);
        BAR();
        // ph8: T1 quad (1,1)
        if (!last) { STAGE_B(T1 + 2, 1, 2); STAGE_B(T1 + 2, 1, 3); }
        BAR();
        MFMA_Q(1, 1);
        if (!last) { WAIT_VM(4); }
        BAR();
    }

    // -------- epilogue: RoPE + store ----------------------------------------
    // C/D layout (16x16): col = lane&15 (=fr), row = (lane>>4)*4 + r
#pragma unroll
    for (int qi = 0; qi < 2; ++qi)
#pragma unroll
    for (int i = 0; i < 4; ++i) {
        int mbase = m0 + wr * 128 + qi * 64 + i * 16 + fq * 4;
#pragma unroll
        for (int qj = 0; qj < 2; ++qj)
#pragma unroll
        for (int j = 0; j < 2; ++j) {
            int n = n0 + wc * 64 + qj * 32 + j * 16 + fr;
            int region = n >> 11;            // 0=q,1=k,2=v
            int cc = n & (DIM_ - 1);
            int d  = cc & (HD_ - 1);
#pragma unroll
            for (int r = 0; r < 4; ++r) {
                int m = mbase + r;
                int s = m & (S_ - 1);
                float g  = acc[qi][qj][i][j][r];
                float gp = __shfl_xor(g, 1, 64);  // interleaved pair partner
                float o;
                if (region < 2) {
                    float cv = fcos[s * HD_ + d];
                    float sv = fsin[s * HD_ + d];
                    o = g * cv + ((cc & 1) ? gp * sv : -gp * sv);
                } else {
                    o = g;
                }
                out[(size_t)region * M_ * DIM_ + (size_t)m * DIM_ + cc] = o;
            }
        }
    }
#undef STAGE_A
#undef STAGE_B
#undef LDA
#undef LDB
#undef MFMA_Q
}

// ---------------------------------------------------------------------------
extern "C" void kernel_launch(void* const* d_in, const int* in_sizes, int n_in,
                              void* d_out, int out_size, void* d_ws, size_t ws_size,
                              hipStream_t stream) {
    const float* X    = (const float*)d_in[0];
    const float* fcos = (const float*)d_in[1];
    const float* fsin = (const float*)d_in[2];
    // d_in[3] = attention_mask (all ones, unused by the reference math)
    const float* Wq   = (const float*)d_in[4];
    const float* Wk   = (const float*)d_in[5];
    const float* Wv   = (const float*)d_in[6];
    float* out = (float*)d_out;

    __hip_bfloat16* Xb  = (__hip_bfloat16*)d_ws;
    __hip_bfloat16* Wtp = Xb + (size_t)M_ * K_;

    {
        int threads = 256;
        int blocks = (M_ * K_) / (threads * 8);   // 16384
        cvt_x_kernel<<<blocks, threads, 0, stream>>>(X, Xb);
    }
    {
        dim3 grid(DIM_ / 32, DIM_ / 32, 3);
        dim3 block(32, 8);
        cvt_w_kernel<<<grid, block, 0, stream>>>(Wq, Wk, Wv, Wtp);
    }
    {
        int blocks = (M_ / BM) * (N_ / BN);       // 64 * 24 = 1536
        gemm_rope_kernel<<<blocks, 512, 0, stream>>>(Xb, Wtp, fcos, fsin, out);
    }
}